// Round 1
// baseline (353.343 us; speedup 1.0000x reference)
//
#include <hip/hip_runtime.h>

#define IMG_H 224
#define IMG_W 224
#define HW (IMG_H * IMG_W)
#define NUM_ROWS 159
#define NUM_COLS 1024
#define BATCH 128

// ---------------------------------------------------------------------------
// Setup: build per-ring pixel lists. ring_pix[d*NUM_COLS + j] = flat pixel
// index of the j-th pixel (row-major order) with round(dist)==d; ring_cnt[d]
// = ring size. One block per ring, 1024 threads, ballot-scan compaction.
// Must be re-run every launch (d_ws is re-poisoned by the harness).
// ---------------------------------------------------------------------------
__global__ __launch_bounds__(1024) void build_rings(int* __restrict__ ring_pix,
                                                    int* __restrict__ ring_cnt) {
    const int d = blockIdx.x;
    const int tid = threadIdx.x;
    __shared__ int wsum[16];
    int base = 0;
    for (int c = 0; c < HW; c += 1024) {
        const int p = c + tid;
        bool in = false;
        if (p < HW) {
            const int y = p / IMG_W;
            const int x = p - y * IMG_W;
            const float dx = (float)(x - 112);
            const float dy = (float)(y - 112);
            // sqrt(integer) is never within 7.9e-4 of k+0.5, f32 error ~1e-5:
            // rounding mode (half-even vs away) is irrelevant here.
            const int dist = (int)roundf(sqrtf(dx * dx + dy * dy));
            in = (dist == d);
        }
        const unsigned long long ball = __ballot(in);
        const int lane = tid & 63;
        const int wid = tid >> 6;
        if (lane == 0) wsum[wid] = __popcll(ball);
        __syncthreads();
        int off = base;
        for (int w = 0; w < wid; ++w) off += wsum[w];
        int tot = 0;
        for (int w = 0; w < 16; ++w) tot += wsum[w];
        if (in) {
            const int j = off + __popcll(ball & ((1ull << lane) - 1ull));
            ring_pix[d * NUM_COLS + j] = p;
        }
        base += tot;
        __syncthreads();  // protect wsum reuse
    }
    if (tid == 0) ring_cnt[d] = base;
}

// ---------------------------------------------------------------------------
// Main: one block per (batch, ring). Gather selected pixels (stable ballot-
// scan compaction in ax2 order), bitonic-sort by 64-bit key
// (prand_bits << 32 | ax2)  == stable lexicographic (prand, column) order,
// then scatter sorted values back into the selected slots in ax2 order.
// Unselected pixels pass through unchanged.
// ---------------------------------------------------------------------------
__global__ __launch_bounds__(256) void radial_shuffle(
    const float* __restrict__ img, const float* __restrict__ mask,
    const float* __restrict__ prand, float* __restrict__ out,
    const int* __restrict__ ring_pix, const int* __restrict__ ring_cnt) {
    const int bd = blockIdx.x;
    const int d = bd % NUM_ROWS;
    const int b = bd / NUM_ROWS;
    const int tid = threadIdx.x;
    const int n = ring_cnt[d];  // <= ~703 < NUM_COLS

    __shared__ unsigned long long skey[NUM_COLS];  // 8 KB
    __shared__ float sval[NUM_COLS];               // 4 KB
    __shared__ int sdst[NUM_COLS];                 // 4 KB
    __shared__ int wsum[4];

    const float* imgb  = img  + (size_t)b * HW;
    const float* maskb = mask + (size_t)b * HW;
    const float* prb   = prand + ((size_t)b * NUM_ROWS + d) * NUM_COLS;
    float* outb = out + (size_t)b * HW;

    // ---- gather + stable compaction of selected pixels ----
    int base = 0;
    for (int c = 0; c < n; c += 256) {
        const int i = c + tid;
        bool sel = false;
        int p = 0;
        float v = 0.f;
        unsigned kb = 0;
        if (i < n) {
            p = ring_pix[d * NUM_COLS + i];
            const float m = maskb[p];
            v = imgb[p];
            sel = (m < 0.5f);
            if (sel) {
                kb = __float_as_uint(prb[i]);  // prand >= 0: bits are order-preserving
            } else {
                outb[p] = v;  // pass-through
            }
        }
        const unsigned long long ball = __ballot(sel);
        const int lane = tid & 63;
        const int wid = tid >> 6;
        if (lane == 0) wsum[wid] = __popcll(ball);
        __syncthreads();
        int off = base;
        for (int w = 0; w < wid; ++w) off += wsum[w];
        const int tot = wsum[0] + wsum[1] + wsum[2] + wsum[3];
        if (sel) {
            const int j = off + __popcll(ball & ((1ull << lane) - 1ull));
            skey[j] = ((unsigned long long)kb << 32) | (unsigned)i;
            sval[j] = v;
            sdst[j] = p;
        }
        base += tot;
        __syncthreads();  // protect wsum reuse
    }
    const int k = base;

    // ---- pad to power of two and bitonic sort ascending on skey ----
    int P = 1;
    while (P < k) P <<= 1;
    for (int j = k + tid; j < P; j += 256) skey[j] = ~0ull;  // +inf sentinels
    __syncthreads();

    for (int size = 2; size <= P; size <<= 1) {
        for (int stride = size >> 1; stride > 0; stride >>= 1) {
            for (int t = tid; t < (P >> 1); t += 256) {
                const int lo = ((t & ~(stride - 1)) << 1) | (t & (stride - 1));
                const int hi = lo + stride;
                const bool asc = ((lo & size) == 0);
                const unsigned long long ka = skey[lo];
                const unsigned long long kb2 = skey[hi];
                const bool do_swap = asc ? (ka > kb2) : (ka < kb2);
                if (do_swap) {
                    skey[lo] = kb2;
                    skey[hi] = ka;
                    const float va = sval[lo];
                    sval[lo] = sval[hi];
                    sval[hi] = va;
                }
            }
            __syncthreads();
        }
    }

    // ---- scatter sorted values back to the selected slots (ax2 order) ----
    for (int j = tid; j < k; j += 256) outb[sdst[j]] = sval[j];
}

extern "C" void kernel_launch(void* const* d_in, const int* in_sizes, int n_in,
                              void* d_out, int out_size, void* d_ws, size_t ws_size,
                              hipStream_t stream) {
    const float* img   = (const float*)d_in[0];  // (128,224,224,1) f32
    const float* mask  = (const float*)d_in[1];  // (128,224,224)   f32
    const float* prand = (const float*)d_in[2];  // (128,159,1024)  f32
    float* out = (float*)d_out;                  // (128,224,224,1) f32

    int* ring_pix = (int*)d_ws;                       // 159*1024*4 B
    int* ring_cnt = ring_pix + NUM_ROWS * NUM_COLS;   // 159*4 B

    hipLaunchKernelGGL(build_rings, dim3(NUM_ROWS), dim3(1024), 0, stream,
                       ring_pix, ring_cnt);
    hipLaunchKernelGGL(radial_shuffle, dim3(BATCH * NUM_ROWS), dim3(256), 0, stream,
                       img, mask, prand, out, ring_pix, ring_cnt);
}

// Round 3
// 273.069 us; speedup vs baseline: 1.2940x; 1.2940x over previous
//
#include <hip/hip_runtime.h>

#define IMG_H 224
#define IMG_W 224
#define HW (IMG_H * IMG_W)
#define NUM_ROWS 159
#define NUM_COLS 1024
#define BATCH 128
#define NUM_XCD 8

// Exact integer sqrt (v <= ~25k here, f32 sqrt + fixup loops).
__device__ __forceinline__ int isqrt_i(int v) {
    int u = (int)sqrtf((float)v);
    while (u > 0 && u * u > v) --u;
    while ((u + 1) * (u + 1) <= v) ++u;
    return u;
}

// ---------------------------------------------------------------------------
// Analytic ring build. round(sqrt(dx^2+dy^2)) == d
//   <=>  Araw <= dx^2+dy^2 <= d^2+d,  Araw = (d==0 ? 0 : d^2-d+1)
// (lower bound from (d-0.5)^2 < r2 is VACUOUS for d=0 — sqrt >= 0 > -0.5;
//  missing this dropped the center pixel in R2). Exact integers, no FP ties.
// For fixed (d, y): |dx| in [lo, hi] -> at most two x-intervals. One block
// per ring: per-row counts, block scan, interval fill. Row-major order ==
// reference ax2 order.
// ---------------------------------------------------------------------------
__global__ __launch_bounds__(256) void build_rings(int* __restrict__ ring_pix,
                                                   int* __restrict__ ring_cnt) {
    const int d = blockIdx.x;
    const int tid = threadIdx.x;  // y = tid for tid < 224
    __shared__ int scnt[256];

    int cnt = 0;
    int x0l = 0, x1l = -1, x0r = 0, x1r = -1;
    if (tid < IMG_H) {
        const int dy = tid - 112;
        const int Araw = (d == 0) ? 0 : (d * d - d + 1);
        int A = Araw - dy * dy;
        if (A < 0) A = 0;
        const int B = d * d + d - dy * dy;
        if (B >= 0) {
            const int hi = isqrt_i(B);
            int lo = isqrt_i(A);
            if (lo * lo < A) ++lo;
            if (lo <= hi) {
                if (lo == 0) {
                    x0l = 112 - min(hi, 112);
                    x1l = 112 + min(hi, 111);
                } else {
                    x0l = 112 - min(hi, 112);
                    x1l = 112 - lo;
                    x0r = 112 + lo;
                    x1r = 112 + min(hi, 111);
                }
                cnt = max(0, x1l - x0l + 1) + max(0, x1r - x0r + 1);
            }
        }
    }
    scnt[tid] = cnt;
    __syncthreads();
    // Hillis-Steele inclusive scan over 256
    for (int off = 1; off < 256; off <<= 1) {
        const int mine = scnt[tid];
        const int add = (tid >= off) ? scnt[tid - off] : 0;
        __syncthreads();
        scnt[tid] = mine + add;
        __syncthreads();
    }
    if (tid < IMG_H && cnt > 0) {
        int j = d * NUM_COLS + (scnt[tid] - cnt);
        const int rowbase = tid * IMG_W;
        for (int x = x0l; x <= x1l; ++x) ring_pix[j++] = rowbase + x;
        for (int x = x0r; x <= x1r; ++x) ring_pix[j++] = rowbase + x;
    }
    if (tid == 255) ring_cnt[d] = scnt[255];
}

// ---------------------------------------------------------------------------
// Main: one block per (batch, ring), XCD-swizzled so each XCD owns 16 whole
// images (L2 write-combining + read sharing for img/mask/out lines).
// Gather + stable ballot-scan compaction; key-only bitonic sort on
// (prand_bits<<32 | ring_col); scatter via column-indexed value lookup.
// ---------------------------------------------------------------------------
__global__ __launch_bounds__(256) void radial_shuffle(
    const float* __restrict__ img, const float* __restrict__ mask,
    const float* __restrict__ prand, float* __restrict__ out,
    const int* __restrict__ ring_pix, const int* __restrict__ ring_cnt) {
    // 20352 blocks = 8 XCDs x (16 images x 159 rings)
    const int xcd = blockIdx.x & (NUM_XCD - 1);
    const int r = blockIdx.x >> 3;             // 0..2543
    const int b = xcd * (BATCH / NUM_XCD) + r / NUM_ROWS;
    const int d = r % NUM_ROWS;
    const int tid = threadIdx.x;
    const int n = ring_cnt[d];

    __shared__ unsigned long long skey[NUM_COLS];  // 8 KB: prand_bits<<32 | col
    __shared__ float sval[NUM_COLS];               // 4 KB: value by ring column
    __shared__ int sdst[NUM_COLS];                 // 4 KB: dst pixel by compact j
    __shared__ int wsum[4];

    const float* imgb  = img  + (size_t)b * HW;
    const float* maskb = mask + (size_t)b * HW;
    const float* prb   = prand + ((size_t)b * NUM_ROWS + d) * NUM_COLS;
    float* outb = out + (size_t)b * HW;

    // ---- gather + stable compaction of selected pixels ----
    int base = 0;
    for (int c = 0; c < n; c += 256) {
        const int i = c + tid;
        bool sel = false;
        int p = 0;
        unsigned kb = 0;
        if (i < n) {
            p = ring_pix[d * NUM_COLS + i];
            const float v = imgb[p];
            kb = __float_as_uint(prb[i]);  // prand >= 0: bits order-preserving
            sel = (maskb[p] < 0.5f);
            if (sel) sval[i] = v;          // value by ring column
            else outb[p] = v;              // pass-through
        }
        const unsigned long long ball = __ballot(sel);
        const int lane = tid & 63;
        const int wid = tid >> 6;
        if (lane == 0) wsum[wid] = __popcll(ball);
        __syncthreads();
        int off = base;
        for (int w = 0; w < wid; ++w) off += wsum[w];
        const int tot = wsum[0] + wsum[1] + wsum[2] + wsum[3];
        if (sel) {
            const int j = off + __popcll(ball & ((1ull << lane) - 1ull));
            skey[j] = ((unsigned long long)kb << 32) | (unsigned)i;
            sdst[j] = p;
        }
        base += tot;
        __syncthreads();  // protect wsum reuse
    }
    const int k = base;

    // ---- pad to power of two, key-only bitonic sort ascending ----
    int P = 1;
    while (P < k) P <<= 1;
    for (int j = k + tid; j < P; j += 256) skey[j] = ~0ull;
    __syncthreads();

    for (int size = 2; size <= P; size <<= 1) {
        for (int stride = size >> 1; stride > 0; stride >>= 1) {
            for (int t = tid; t < (P >> 1); t += 256) {
                const int lo = ((t & ~(stride - 1)) << 1) | (t & (stride - 1));
                const int hi = lo + stride;
                const bool asc = ((lo & size) == 0);
                const unsigned long long ka = skey[lo];
                const unsigned long long kc = skey[hi];
                if (asc ? (ka > kc) : (ka < kc)) {
                    skey[lo] = kc;
                    skey[hi] = ka;
                }
            }
            __syncthreads();
        }
    }

    // ---- scatter: j-th smallest key's value -> j-th selected slot ----
    for (int j = tid; j < k; j += 256) {
        const unsigned col = (unsigned)skey[j];  // low 32 bits = ring column
        outb[sdst[j]] = sval[col];
    }
}

extern "C" void kernel_launch(void* const* d_in, const int* in_sizes, int n_in,
                              void* d_out, int out_size, void* d_ws, size_t ws_size,
                              hipStream_t stream) {
    const float* img   = (const float*)d_in[0];  // (128,224,224,1) f32
    const float* mask  = (const float*)d_in[1];  // (128,224,224)   f32
    const float* prand = (const float*)d_in[2];  // (128,159,1024)  f32
    float* out = (float*)d_out;                  // (128,224,224,1) f32

    int* ring_pix = (int*)d_ws;                       // 159*1024*4 B
    int* ring_cnt = ring_pix + NUM_ROWS * NUM_COLS;   // 159*4 B

    hipLaunchKernelGGL(build_rings, dim3(NUM_ROWS), dim3(256), 0, stream,
                       ring_pix, ring_cnt);
    hipLaunchKernelGGL(radial_shuffle, dim3(BATCH * NUM_ROWS), dim3(256), 0, stream,
                       img, mask, prand, out, ring_pix, ring_cnt);
}

// Round 4
// 271.473 us; speedup vs baseline: 1.3016x; 1.0059x over previous
//
#include <hip/hip_runtime.h>

#define IMG_H 224
#define IMG_W 224
#define HW (IMG_H * IMG_W)
#define NUM_ROWS 159
#define NUM_COLS 1024
#define BATCH 128
#define OVF_CAP 4096

// Exact integer sqrt (v <= ~25k here, f32 sqrt + fixup loops).
__device__ __forceinline__ int isqrt_i(int v) {
    int u = (int)sqrtf((float)v);
    while (u > 0 && u * u > v) --u;
    while ((u + 1) * (u + 1) <= v) ++u;
    return u;
}

// ---------------------------------------------------------------------------
// Analytic ring build (verified R3). round(sqrt(dx^2+dy^2)) == d
//   <=>  Araw <= dx^2+dy^2 <= d^2+d,  Araw = (d==0 ? 0 : d^2-d+1)
// Also zeroes the overflow counter (runs before radial_shuffle in stream).
// ---------------------------------------------------------------------------
__global__ __launch_bounds__(256) void build_rings(int* __restrict__ ring_pix,
                                                   int* __restrict__ ring_cnt,
                                                   int* __restrict__ ovf_cnt) {
    const int d = blockIdx.x;
    const int tid = threadIdx.x;  // y = tid for tid < 224
    __shared__ int scnt[256];
    if (d == 0 && tid == 0) ovf_cnt[0] = 0;

    int cnt = 0;
    int x0l = 0, x1l = -1, x0r = 0, x1r = -1;
    if (tid < IMG_H) {
        const int dy = tid - 112;
        const int Araw = (d == 0) ? 0 : (d * d - d + 1);
        int A = Araw - dy * dy;
        if (A < 0) A = 0;
        const int B = d * d + d - dy * dy;
        if (B >= 0) {
            const int hi = isqrt_i(B);
            int lo = isqrt_i(A);
            if (lo * lo < A) ++lo;
            if (lo <= hi) {
                if (lo == 0) {
                    x0l = 112 - min(hi, 112);
                    x1l = 112 + min(hi, 111);
                } else {
                    x0l = 112 - min(hi, 112);
                    x1l = 112 - lo;
                    x0r = 112 + lo;
                    x1r = 112 + min(hi, 111);
                }
                cnt = max(0, x1l - x0l + 1) + max(0, x1r - x0r + 1);
            }
        }
    }
    scnt[tid] = cnt;
    __syncthreads();
    for (int off = 1; off < 256; off <<= 1) {
        const int mine = scnt[tid];
        const int add = (tid >= off) ? scnt[tid - off] : 0;
        __syncthreads();
        scnt[tid] = mine + add;
        __syncthreads();
    }
    if (tid < IMG_H && cnt > 0) {
        int j = d * NUM_COLS + (scnt[tid] - cnt);
        const int rowbase = tid * IMG_W;
        for (int x = x0l; x <= x1l; ++x) ring_pix[j++] = rowbase + x;
        for (int x = x0r; x <= x1r; ++x) ring_pix[j++] = rowbase + x;
    }
    if (tid == 255) ring_cnt[d] = scnt[255];
}

// ---------------------------------------------------------------------------
// Per-wave gather + stable compaction. Key = prand_bits(31b) << 16 | pixel
// (pixel < 50176 fits 16b and is monotone in ring column -> exact stable
// tie-break). Writes pass-through pixels directly. Returns k (#selected).
// ---------------------------------------------------------------------------
__device__ __forceinline__ int gather_ring(
    int b, int d, int lane, int cap,
    const float* __restrict__ img, const float* __restrict__ mask,
    const float* __restrict__ prand, float* __restrict__ out,
    const int* __restrict__ ring_pix, int n,
    unsigned long long* __restrict__ wskey) {
    const float* imgb  = img  + (size_t)b * HW;
    const float* maskb = mask + (size_t)b * HW;
    const float* prb   = prand + ((size_t)b * NUM_ROWS + d) * NUM_COLS;
    float* outb = out + (size_t)b * HW;
    const unsigned long long ltmask = (1ull << lane) - 1ull;
    int base = 0;
    for (int c = 0; c < n; c += 64) {
        const int i = c + lane;
        bool sel = false;
        int p = 0;
        unsigned kb = 0;
        if (i < n) {
            p = ring_pix[d * NUM_COLS + i];
            const float v = imgb[p];
            kb = __float_as_uint(prb[i]);  // prand in [0,1): bits order-preserving
            sel = (maskb[p] < 0.5f);
            if (!sel) outb[p] = v;         // pass-through
        }
        const unsigned long long ball = __ballot(sel);
        if (sel) {
            const int j = base + __popcll(ball & ltmask);
            if (j < cap) wskey[j] = ((unsigned long long)kb << 16) | (unsigned)p;
        }
        base += __popcll(ball);
    }
    return base;
}

// ---------------------------------------------------------------------------
// Wave-level bitonic sort of P = 64*E keys (E per lane, blocked layout
// pos = lane*E + e) + scatter. Cross-lane strides (>= E) via __shfl_xor
// (always within the 64-lane wave); strides < E are in-register (VALU only).
// No barriers, no bank conflicts. Pre-sort low16 of slot j = dst pixel of
// rank j; post-sort low16 = src pixel of rank j.
// ---------------------------------------------------------------------------
template <int LOGE>
__device__ void sort_scatter(const unsigned long long* __restrict__ wskey,
                             int k, int lane,
                             const float* __restrict__ imgb,
                             float* __restrict__ outb) {
    constexpr int E = 1 << LOGE;
    const int P = 64 << LOGE;
    const int base = lane << LOGE;
    unsigned long long key[E];
    unsigned short dstp[E];
#pragma unroll
    for (int e = 0; e < E; ++e) {
        const int j = base + e;
        const unsigned long long kv = (j < k) ? wskey[j] : ~0ull;
        key[e] = kv;
        dstp[e] = (unsigned short)kv;
    }
    for (int size = 2; size <= P; size <<= 1) {
        const bool upw = ((base & size) == 0);  // e bits < size for cross-lane stages
        for (int stride = size >> 1; stride >= E; stride >>= 1) {
            const int lx = stride >> LOGE;
            const bool keepmin = (((lane & lx) == 0) == upw);
#pragma unroll
            for (int e = 0; e < E; ++e) {
                const unsigned long long mine = key[e];
                const unsigned long long other = __shfl_xor(mine, lx, 64);
                const unsigned long long lo = mine < other ? mine : other;
                const unsigned long long hi = mine < other ? other : mine;
                key[e] = keepmin ? lo : hi;
            }
        }
#pragma unroll
        for (int sbit = LOGE - 1; sbit >= 0; --sbit) {
            const int s = 1 << sbit;
            if (s < size) {  // stride s participates in this pass
#pragma unroll
                for (int e = 0; e < E; ++e) {
                    if ((e & s) == 0) {
                        const int f = e | s;
                        const bool up = (((base | e) & size) == 0);
                        const unsigned long long a = key[e];
                        const unsigned long long b = key[f];
                        const unsigned long long lo = a < b ? a : b;
                        const unsigned long long hi = a < b ? b : a;
                        key[e] = up ? lo : hi;
                        key[f] = up ? hi : lo;
                    }
                }
            }
        }
    }
#pragma unroll
    for (int e = 0; e < E; ++e) {
        const int j = base + e;
        if (j < k) {
            const int psrc = (int)(key[e] & 0xFFFFull);
            outb[dstp[e]] = imgb[psrc];  // imgb L1-hot from gather
        }
    }
}

// ---------------------------------------------------------------------------
// Main: one WAVE per (batch, ring); 4 waves/block; XCD-swizzled (16 whole
// images per XCD). LDS = 4 x 512-key staging only (16 KB). Two barriers
// per block total.
// ---------------------------------------------------------------------------
__global__ __launch_bounds__(256) void radial_shuffle(
    const float* __restrict__ img, const float* __restrict__ mask,
    const float* __restrict__ prand, float* __restrict__ out,
    const int* __restrict__ ring_pix, const int* __restrict__ ring_cnt,
    int* __restrict__ ovf_cnt, int* __restrict__ ovf_list) {
    const int tid = threadIdx.x;
    const int wid = tid >> 6;
    const int lane = tid & 63;
    // 5088 blocks = 8 XCDs x 636; each wave owns one (b,d)
    const int xcd = blockIdx.x & 7;
    const int g = (blockIdx.x >> 3) * 4 + wid;  // 0..2543 within XCD
    const int b = xcd * (BATCH / 8) + g / NUM_ROWS;
    const int d = g % NUM_ROWS;
    const int n = ring_cnt[d];

    __shared__ unsigned long long skey_s[4][512];  // 16 KB
    unsigned long long* wskey = skey_s[wid];

    const int k = gather_ring(b, d, lane, 512, img, mask, prand, out,
                              ring_pix, n, wskey);
    __syncthreads();  // LDS visibility before register load

    if (k > 512) {
        // ~+12 sigma binomial tail: never in practice; defer to overflow kernel
        if (lane == 0) {
            const int idx = atomicAdd(ovf_cnt, 1);
            if (idx < OVF_CAP) ovf_list[idx] = b * NUM_ROWS + d;
        }
    } else if (k > 0) {
        const float* imgb = img + (size_t)b * HW;
        float* outb = out + (size_t)b * HW;
        if (k <= 64)       sort_scatter<0>(wskey, k, lane, imgb, outb);
        else if (k <= 128) sort_scatter<1>(wskey, k, lane, imgb, outb);
        else if (k <= 256) sort_scatter<2>(wskey, k, lane, imgb, outb);
        else               sort_scatter<3>(wskey, k, lane, imgb, outb);
    }
}

// Cold path: rings with k > 512 (capacity 768 >= max ring 703). One wave per
// block, E=16 sort. Separate kernel so its VGPR cost doesn't touch the hot one.
__global__ __launch_bounds__(64) void overflow_sort(
    const float* __restrict__ img, const float* __restrict__ mask,
    const float* __restrict__ prand, float* __restrict__ out,
    const int* __restrict__ ring_pix, const int* __restrict__ ring_cnt,
    const int* __restrict__ ovf_cnt, const int* __restrict__ ovf_list) {
    __shared__ unsigned long long wskey[768];
    const int m = min(*ovf_cnt, OVF_CAP);
    const int lane = threadIdx.x;
    for (int t = blockIdx.x; t < m; t += gridDim.x) {
        const int bd = ovf_list[t];
        const int b = bd / NUM_ROWS;
        const int d = bd % NUM_ROWS;
        const int k = gather_ring(b, d, lane, 768, img, mask, prand, out,
                                  ring_pix, ring_cnt[d], wskey);
        __syncthreads();
        sort_scatter<4>(wskey, k, lane, img + (size_t)b * HW, out + (size_t)b * HW);
        __syncthreads();  // before wskey reuse
    }
}

extern "C" void kernel_launch(void* const* d_in, const int* in_sizes, int n_in,
                              void* d_out, int out_size, void* d_ws, size_t ws_size,
                              hipStream_t stream) {
    const float* img   = (const float*)d_in[0];  // (128,224,224,1) f32
    const float* mask  = (const float*)d_in[1];  // (128,224,224)   f32
    const float* prand = (const float*)d_in[2];  // (128,159,1024)  f32
    float* out = (float*)d_out;                  // (128,224,224,1) f32

    int* ring_pix = (int*)d_ws;                       // 159*1024 ints
    int* ring_cnt = ring_pix + NUM_ROWS * NUM_COLS;   // 159 ints
    int* ovf_cnt  = ring_cnt + NUM_ROWS;              // 1 int
    int* ovf_list = ovf_cnt + 1;                      // OVF_CAP ints

    hipLaunchKernelGGL(build_rings, dim3(NUM_ROWS), dim3(256), 0, stream,
                       ring_pix, ring_cnt, ovf_cnt);
    hipLaunchKernelGGL(radial_shuffle, dim3(BATCH * NUM_ROWS / 4), dim3(256), 0,
                       stream, img, mask, prand, out, ring_pix, ring_cnt,
                       ovf_cnt, ovf_list);
    hipLaunchKernelGGL(overflow_sort, dim3(32), dim3(64), 0, stream,
                       img, mask, prand, out, ring_pix, ring_cnt,
                       ovf_cnt, ovf_list);
}